// Round 4
// baseline (777.729 us; speedup 1.0000x reference)
//
#include <hip/hip_runtime.h>

#define T_ 30
#define H_ 41
#define WD_ 2048
#define NSEC 9
#define KH 6
#define KW 40
#define FM 50
#define WP 502            // pooled width
#define THRESH 23.0f
#define XT 296            // LDS x-tile cols (256 + 39 halo, rounded to 296)
#define POOLED_SIZE (NSEC * T_ * FM * WP)   // 6,777,000

// ---------------- Kernel A: conv + threshold + 4x4 max-pool ----------------
// block: 256 = 64 pooled-cols x 4 feature maps (fm wave-uniform -> scalar W)
// grid : 9 sec * 30 t * 13 fm-groups * 8 w-tiles = 28080
// R4: col-step-outer (5 x 8 kernel cols): weights hoisted to 6 uniform
//     s_load_dwordx8 per step (48 SGPRs), zero in-loop scalar traffic.
//     R3's 240 in-loop s_load_dwordx4 serialized lgkmcnt against ds_read
//     (654 us vs ~400 us VALU-bound account). x: 135 ds_read_b128/thread.
__global__ __launch_bounds__(256) void conv_pool_kernel(
    const float* __restrict__ x, const float* __restrict__ Wg,
    float* __restrict__ out)
{
    __shared__ float lx[9 * XT];      // 9 rows x 296 cols = 10.4 KB

    const int b   = blockIdx.x;
    const int wt  = b & 7;            // 8 w-tiles
    const int fmg = (b >> 3) % 13;    // 13 fm-groups of 4
    const int tt  = (b / 104) % T_;
    const int sec = b / 3120;

    const int tid     = threadIdx.x;
    const int colbase = wt * 256;     // pot-col base of this tile
    const int rowbase = 4 * sec;

    // stage x tile: 9 rows x 74 float4
    for (int i = tid; i < 9 * 74; i += 256) {
        const int row  = i / 74;
        const int c4   = i % 74;
        const int gcol = colbase + 4 * c4;
        float4 v;
        if (gcol + 3 < WD_) {
            v = *reinterpret_cast<const float4*>(
                x + (size_t)(tt * H_ + rowbase + row) * WD_ + gcol);
        } else {
            v.x = v.y = v.z = v.w = 0.f;
        }
        *reinterpret_cast<float4*>(&lx[row * XT + 4 * c4]) = v;
    }
    __syncthreads();

    const int wpl = tid & 63;    // pooled col within tile (wave-contiguous)
    const int fl  = tid >> 6;    // fm within group (wave-uniform!)
    const int fm0 = fmg * 4;
    const int fm  = fm0 + fl;

    // force scalar (SGPR) weight address: fm is uniform across the wave
    int fm_u = __builtin_amdgcn_readfirstlane(fm);
    fm_u = fm_u < FM ? fm_u : FM - 1;   // clamp OOB fm (50,51); discarded at store
    const float* __restrict__ wsec = Wg + (size_t)(sec * FM + fm_u) * 240;

    float acc[4][4];             // [pot row j][pot col wi]
#pragma unroll
    for (int j = 0; j < 4; ++j)
#pragma unroll
        for (int wi = 0; wi < 4; ++wi) acc[j][wi] = 0.f;

    const float* xbase = &lx[4 * wpl];

#pragma unroll 1
    for (int s = 0; s < 5; ++s) {     // kernel-col step: cols 8s .. 8s+7
        // hoisted uniform weight loads: 6 rows x 8 cols -> SGPRs
        float wv[6][8];
#pragma unroll
        for (int r = 0; r < 6; ++r) {
#pragma unroll
            for (int c = 0; c < 8; ++c)
                wv[r][c] = wsec[r * 40 + 8 * s + c];
        }

#pragma unroll
        for (int a = 0; a < 9; ++a) { // x row within section (compile-time)
            const int jlo = (a - 5 > 0) ? a - 5 : 0;
            const int jhi = (a < 3) ? a : 3;
            const float* xr = xbase + a * XT + 8 * s;

            float xw[12];             // x cols 4*wpl+8s .. +11
            {
                float4 c0 = *reinterpret_cast<const float4*>(xr);
                float4 c1 = *reinterpret_cast<const float4*>(xr + 4);
                float4 c2 = *reinterpret_cast<const float4*>(xr + 8);
                xw[0] = c0.x; xw[1] = c0.y; xw[2]  = c0.z; xw[3]  = c0.w;
                xw[4] = c1.x; xw[5] = c1.y; xw[6]  = c1.z; xw[7]  = c1.w;
                xw[8] = c2.x; xw[9] = c2.y; xw[10] = c2.z; xw[11] = c2.w;
            }
#pragma unroll
            for (int j = jlo; j <= jhi; ++j) {   // pot row; weight row r=a-j
                const int r = a - j;
#pragma unroll
                for (int c = 0; c < 8; ++c) {
#pragma unroll
                    for (int wi = 0; wi < 4; ++wi)
                        acc[j][wi] = fmaf(xw[c + wi], wv[r][c], acc[j][wi]);
                }
            }
        }
    }

    bool any = false;
#pragma unroll
    for (int j = 0; j < 4; ++j)
#pragma unroll
        for (int wi = 0; wi < 4; ++wi) any = any || (acc[j][wi] > THRESH);

    const int wp_real = wt * 64 + wpl;
    if (wp_real < WP && fm < FM) {
        out[((size_t)(sec * T_ + tt) * FM + fm) * WP + wp_real] = any ? 1.0f : 0.0f;
    }
}

// ---------------- Kernel B: init workspace ----------------
__global__ void init_kernel(int* __restrict__ ws)
{
    if (threadIdx.x < NSEC) ws[threadIdx.x] = 0x7fffffff;
}

// ---------------- Kernel C: first-spike scan + argmin reduce ----------------
// grid: 9 sections * 99 blocks (blocks never cross a section)
__global__ __launch_bounds__(256) void scan_kernel(
    const float* __restrict__ pooled, int* __restrict__ ws)
{
    __shared__ int sk[256];
    const int sec = blockIdx.x / 99;
    const int bi  = blockIdx.x % 99;
    const int e   = bi * 256 + threadIdx.x;   // flat (fm*WP + wp) within section
    int key = 0x7fffffff;
    if (e < FM * WP) {
        const int fm = e / WP;
        const int wp = e % WP;
        const size_t base = ((size_t)(sec * T_) * FM + fm) * WP + wp;
        const size_t tstride = (size_t)FM * WP;
#pragma unroll 1
        for (int t = 0; t < T_; ++t) {
            if (pooled[base + t * tstride] > 0.f) { key = (t << 15) | e; break; }
        }
    }
    sk[threadIdx.x] = key;
    __syncthreads();
    for (int s = 128; s > 0; s >>= 1) {
        if (threadIdx.x < s) sk[threadIdx.x] = min(sk[threadIdx.x], sk[threadIdx.x + s]);
        __syncthreads();
    }
    if (threadIdx.x == 0) atomicMin(&ws[sec], sk[0]);
}

// ---------------- Kernel D: finalize winners ----------------
__global__ void finalize_kernel(const int* __restrict__ ws, float* __restrict__ out)
{
    const int i = threadIdx.x;
    if (i < NSEC) {
        const int key = ws[i];
        float feat;
        if (key == 0x7fffffff) feat = -1.0f;
        else                   feat = (float)((key & 32767) / WP);
        out[POOLED_SIZE + i] = feat;
    }
}

extern "C" void kernel_launch(void* const* d_in, const int* in_sizes, int n_in,
                              void* d_out, int out_size, void* d_ws, size_t ws_size,
                              hipStream_t stream) {
    const float* x  = (const float*)d_in[0];
    const float* Wg = (const float*)d_in[1];
    float* out = (float*)d_out;
    int*   ws  = (int*)d_ws;

    hipLaunchKernelGGL(init_kernel, dim3(1), dim3(64), 0, stream, ws);
    hipLaunchKernelGGL(conv_pool_kernel, dim3(28080), dim3(256), 0, stream, x, Wg, out);
    hipLaunchKernelGGL(scan_kernel, dim3(NSEC * 99), dim3(256), 0, stream, out, ws);
    hipLaunchKernelGGL(finalize_kernel, dim3(1), dim3(16), 0, stream, ws, out);
}

// Round 5
// 676.131 us; speedup vs baseline: 1.1503x; 1.1503x over previous
//
#include <hip/hip_runtime.h>

#define T_ 30
#define H_ 41
#define WD_ 2048
#define NSEC 9
#define KH 6
#define KW 40
#define FM 50
#define WP 502            // pooled width
#define THRESH 23.0f
#define XT2 552           // LDS x-tile cols: 512 + 39 halo, rounded to 552 (÷8)
#define POOLED_SIZE (NSEC * T_ * FM * WP)   // 6,777,000

// ---------------- Kernel A: conv + threshold + 4x4 max-pool ----------------
// block: 256 = 64 lanes x 4 fm; each lane computes TWO 4-col pot groups
//        (group1 = group0 + 256 pot cols) sharing weights and loop glue.
// grid : 9 sec * 30 t * 13 fm-groups * 4 w-tiles(512 pot cols) = 14040
// R5: R3 was VALU-issue bound (97% busy, ~7000 instr/wave vs 3840 FMA).
//     Dual-group doubles FMA per iteration, halves waves -> amortizes the
//     per-iteration overhead. ds_read stays the proven conflict-free
//     16B-lane-stride b128 pattern. W stays on the in-loop scalar path (R3);
//     R4's hoist put weights in VGPRs (88 VGPR, 23% occ) - do not repeat.
__global__ __launch_bounds__(256) void conv_pool_kernel(
    const float* __restrict__ x, const float* __restrict__ Wg,
    float* __restrict__ out)
{
    __shared__ float lx[9 * XT2];     // 9 rows x 552 cols = 19.9 KB

    const int b   = blockIdx.x;
    const int wt  = b & 3;            // 4 w-tiles of 512 pot cols
    const int fmg = (b >> 2) % 13;    // 13 fm-groups of 4
    const int tt  = (b / 52) % T_;
    const int sec = b / 1560;

    const int tid     = threadIdx.x;
    const int colbase = wt * 512;     // pot-col base of this tile
    const int rowbase = 4 * sec;

    // stage x tile: 9 rows x 138 float4 (cols >= 2048 zero-padded)
    for (int i = tid; i < 9 * 138; i += 256) {
        const int row  = i / 138;
        const int c4   = i % 138;
        const int gcol = colbase + 4 * c4;
        float4 v;
        if (gcol + 3 < WD_) {
            v = *reinterpret_cast<const float4*>(
                x + (size_t)(tt * H_ + rowbase + row) * WD_ + gcol);
        } else {
            v.x = v.y = v.z = v.w = 0.f;
        }
        *reinterpret_cast<float4*>(&lx[row * XT2 + 4 * c4]) = v;
    }
    __syncthreads();

    const int L   = tid & 63;    // lane (wave-contiguous pooled cols)
    const int fl  = tid >> 6;    // fm within group (wave-uniform!)
    const int fm0 = fmg * 4;
    const int fm  = fm0 + fl;

    // force scalar (SGPR) weight address: fm is uniform across the wave
    int fm_u = __builtin_amdgcn_readfirstlane(fm);
    fm_u = fm_u < FM ? fm_u : FM - 1;   // clamp OOB fm (50,51); discarded at store
    const float* __restrict__ wsec = Wg + (size_t)(sec * FM + fm_u) * 240;

    float acc0[4][4], acc1[4][4];   // [pot row j][pot col wi], two groups
#pragma unroll
    for (int j = 0; j < 4; ++j)
#pragma unroll
        for (int wi = 0; wi < 4; ++wi) { acc0[j][wi] = 0.f; acc1[j][wi] = 0.f; }

    const float* xb0 = &lx[4 * L];          // group0: local pot cols 4L..4L+3
    const float* xb1 = &lx[256 + 4 * L];    // group1: +256 pot cols

#pragma unroll
    for (int a = 0; a < 9; ++a) {     // x row within section (compile-time)
        const int jlo = (a - 5 > 0) ? a - 5 : 0;   // folds to consts per a
        const int jhi = (a < 3) ? a : 3;
        const float* xr0 = xb0 + a * XT2;
        const float* xr1 = xb1 + a * XT2;

        float u[8], v[8];
        {
            float4 c0 = *reinterpret_cast<const float4*>(xr0);
            float4 c1 = *reinterpret_cast<const float4*>(xr1);
            u[0] = c0.x; u[1] = c0.y; u[2] = c0.z; u[3] = c0.w;
            v[0] = c1.x; v[1] = c1.y; v[2] = c1.z; v[3] = c1.w;
        }
#pragma unroll 2
        for (int cq = 0; cq < 10; ++cq) {          // kernel cols, chunks of 4
            float4 n0 = *reinterpret_cast<const float4*>(xr0 + 4 * cq + 4);
            float4 n1 = *reinterpret_cast<const float4*>(xr1 + 4 * cq + 4);
            u[4] = n0.x; u[5] = n0.y; u[6] = n0.z; u[7] = n0.w;
            v[4] = n1.x; v[5] = n1.y; v[6] = n1.z; v[7] = n1.w;
#pragma unroll
            for (int j = jlo; j <= jhi; ++j) {     // pot row; weight row r=a-j
                const float* wr = wsec + (a - j) * 40 + 4 * cq;  // scalar addr
                const float w0 = wr[0], w1 = wr[1], w2 = wr[2], w3 = wr[3];
#pragma unroll
                for (int wi = 0; wi < 4; ++wi) {
                    acc0[j][wi] = fmaf(u[0 + wi], w0, acc0[j][wi]);
                    acc0[j][wi] = fmaf(u[1 + wi], w1, acc0[j][wi]);
                    acc0[j][wi] = fmaf(u[2 + wi], w2, acc0[j][wi]);
                    acc0[j][wi] = fmaf(u[3 + wi], w3, acc0[j][wi]);
                    acc1[j][wi] = fmaf(v[0 + wi], w0, acc1[j][wi]);
                    acc1[j][wi] = fmaf(v[1 + wi], w1, acc1[j][wi]);
                    acc1[j][wi] = fmaf(v[2 + wi], w2, acc1[j][wi]);
                    acc1[j][wi] = fmaf(v[3 + wi], w3, acc1[j][wi]);
                }
            }
            u[0] = u[4]; u[1] = u[5]; u[2] = u[6]; u[3] = u[7];
            v[0] = v[4]; v[1] = v[5]; v[2] = v[6]; v[3] = v[7];
        }
    }

    bool any0 = false, any1 = false;
#pragma unroll
    for (int j = 0; j < 4; ++j)
#pragma unroll
        for (int wi = 0; wi < 4; ++wi) {
            any0 = any0 || (acc0[j][wi] > THRESH);
            any1 = any1 || (acc1[j][wi] > THRESH);
        }

    if (fm < FM) {
        const size_t outb = ((size_t)(sec * T_ + tt) * FM + fm) * WP;
        const int wp0 = wt * 128 + L;        // group0 pooled col
        const int wp1 = wp0 + 64;            // group1 pooled col
        if (wp0 < WP) out[outb + wp0] = any0 ? 1.0f : 0.0f;
        if (wp1 < WP) out[outb + wp1] = any1 ? 1.0f : 0.0f;
    }
}

// ---------------- Kernel B: init workspace ----------------
__global__ void init_kernel(int* __restrict__ ws)
{
    if (threadIdx.x < NSEC) ws[threadIdx.x] = 0x7fffffff;
}

// ---------------- Kernel C: first-spike scan + argmin reduce ----------------
// grid: 9 sections * 99 blocks (blocks never cross a section)
__global__ __launch_bounds__(256) void scan_kernel(
    const float* __restrict__ pooled, int* __restrict__ ws)
{
    __shared__ int sk[256];
    const int sec = blockIdx.x / 99;
    const int bi  = blockIdx.x % 99;
    const int e   = bi * 256 + threadIdx.x;   // flat (fm*WP + wp) within section
    int key = 0x7fffffff;
    if (e < FM * WP) {
        const int fm = e / WP;
        const int wp = e % WP;
        const size_t base = ((size_t)(sec * T_) * FM + fm) * WP + wp;
        const size_t tstride = (size_t)FM * WP;
#pragma unroll 1
        for (int t = 0; t < T_; ++t) {
            if (pooled[base + t * tstride] > 0.f) { key = (t << 15) | e; break; }
        }
    }
    sk[threadIdx.x] = key;
    __syncthreads();
    for (int s = 128; s > 0; s >>= 1) {
        if (threadIdx.x < s) sk[threadIdx.x] = min(sk[threadIdx.x], sk[threadIdx.x + s]);
        __syncthreads();
    }
    if (threadIdx.x == 0) atomicMin(&ws[sec], sk[0]);
}

// ---------------- Kernel D: finalize winners ----------------
__global__ void finalize_kernel(const int* __restrict__ ws, float* __restrict__ out)
{
    const int i = threadIdx.x;
    if (i < NSEC) {
        const int key = ws[i];
        float feat;
        if (key == 0x7fffffff) feat = -1.0f;
        else                   feat = (float)((key & 32767) / WP);
        out[POOLED_SIZE + i] = feat;
    }
}

extern "C" void kernel_launch(void* const* d_in, const int* in_sizes, int n_in,
                              void* d_out, int out_size, void* d_ws, size_t ws_size,
                              hipStream_t stream) {
    const float* x  = (const float*)d_in[0];
    const float* Wg = (const float*)d_in[1];
    float* out = (float*)d_out;
    int*   ws  = (int*)d_ws;

    hipLaunchKernelGGL(init_kernel, dim3(1), dim3(64), 0, stream, ws);
    hipLaunchKernelGGL(conv_pool_kernel, dim3(14040), dim3(256), 0, stream, x, Wg, out);
    hipLaunchKernelGGL(scan_kernel, dim3(NSEC * 99), dim3(256), 0, stream, out, ws);
    hipLaunchKernelGGL(finalize_kernel, dim3(1), dim3(16), 0, stream, ws, out);
}

// Round 6
// 432.023 us; speedup vs baseline: 1.8002x; 1.5650x over previous
//
#include <hip/hip_runtime.h>

#define T_ 30
#define H_ 41
#define WD_ 2048
#define NSEC 9
#define FM 50
#define WP 502
#define THRESH 23.0f
#define POOLED_SIZE (NSEC * T_ * FM * WP)   // 6,777,000
#define MARGIN 0.0078125f                   // 2^-7 >= 3.4x worst-case split error

typedef short short8 __attribute__((ext_vector_type(8)));
typedef float f32x4 __attribute__((ext_vector_type(4)));

__device__ __forceinline__ unsigned bf16_rne(float f) {
    unsigned u = __float_as_uint(f);
    return (u + 0x7fffu + ((u >> 16) & 1u)) >> 16;
}

// ---------------- Kernel A: split-bf16 MFMA conv + fire + 4x4 pool ---------
// grid: 270 (sec,t) x 16 coltiles(128 pot cols) = 4320 blocks, 256 thr.
// wave w = pot row j_p. C[m=pot][n=fm] 16x16x32 tiles; m strides pot cols
// by 8 (residues res 0..7 cover the 128). x in LDS as packed (bf16hi<<16|lo)
// u32, 4 col-shifted copies so every residue's 8-col window is a 16B-aligned
// ds_read_b128 pair. W hi/lo frags live in 64 VGPRs per fm-tile, from global.
// Borderline pots (|pot-23| < 2^-7) repaired in exact fp32 (r-major,c-minor,
// same order as the R3/R5 kernels that pass with absmax 0).
__global__ __launch_bounds__(256) void conv_pool_kernel(
    const float* __restrict__ x, const float* __restrict__ Wg,
    float* __restrict__ out)
{
    __shared__ unsigned xls[4][10][176];   // 27.5 KB: [shift S][row][col]
    __shared__ unsigned lmask[4][64];

    const int b       = blockIdx.x;
    const int coltile = b & 15;
    const int tt      = (b >> 4) % T_;
    const int sec     = b / 480;
    const int w0      = coltile * 128;     // pot-col base
    const int rowbase = 4 * sec;
    const int tid     = threadIdx.x;

    // ---- stage x: 10 rows x 176 cols -> packed hi/lo, 4 shifted copies ----
    for (int i = tid; i < 440; i += 256) {
        const int row = i / 44;
        const int c4  = i % 44;
        const int grow = (rowbase + row < H_) ? rowbase + row : H_ - 1;
        const int gc   = w0 + 4 * c4;
        float4 v;
        if (gc + 3 < WD_) {
            v = *reinterpret_cast<const float4*>(x + ((size_t)tt * H_ + grow) * WD_ + gc);
        } else {
            v.x = v.y = v.z = v.w = 0.f;
        }
        float f[4] = {v.x, v.y, v.z, v.w};
        unsigned p[4];
#pragma unroll
        for (int e = 0; e < 4; ++e) {
            unsigned h = bf16_rne(f[e]);
            float hf = __uint_as_float(h << 16);
            unsigned l = bf16_rne(f[e] - hf);
            p[e] = (h << 16) | l;
        }
#pragma unroll
        for (int S = 0; S < 4; ++S)
#pragma unroll
            for (int e = 0; e < 4; ++e) {
                const int j = 4 * c4 + e - S;
                if (j >= 0 && j < 176) xls[S][row][j] = p[e];
            }
    }
    __syncthreads();

    const int L    = tid & 63;
    const int j_p  = tid >> 6;       // wave id = pot row
    const int q    = L >> 4;         // quad
    const int n16  = L & 15;         // A: m-index base; B: fm-index base

    // per-kk tap geometry (tau0 = 32kk + 8q -> weight row r, col c0)
    int preidx[8];                   // dword index into xls[0] (S added later)
    int tau0s[8];
#pragma unroll
    for (int kk = 0; kk < 8; ++kk) {
        const int t0 = 32 * kk + 8 * q;
        const int r  = t0 / 40;
        const int c0 = t0 - 40 * r;
        tau0s[kk]  = t0;
        preidx[kk] = (j_p + r) * 176 + c0 + 8 * n16;
    }

    unsigned mask = 0;

#pragma unroll 1
    for (int ft = 0; ft < 4; ++ft) {
        const int fm = ft * 16 + n16;
        // ---- build W hi/lo frags for this fm-tile (held in regs) ----
        short8 wh[8], wl[8];
#pragma unroll
        for (int kk = 0; kk < 8; ++kk) {
            const int t0 = tau0s[kk];
            const bool wvalid = (t0 < 240) && (fm < FM);
            const float* wp = Wg + (size_t)sec * FM * 240 +
                              (size_t)(wvalid ? fm : 0) * 240 + (wvalid ? t0 : 0);
            float4 wa = *reinterpret_cast<const float4*>(wp);
            float4 wb = *reinterpret_cast<const float4*>(wp + 4);
            float f[8] = {wa.x, wa.y, wa.z, wa.w, wb.x, wb.y, wb.z, wb.w};
            unsigned hh[4], ll[4];
#pragma unroll
            for (int i = 0; i < 4; ++i) {
                float f0 = wvalid ? f[2 * i] : 0.f;
                float f1 = wvalid ? f[2 * i + 1] : 0.f;
                unsigned h0 = bf16_rne(f0), h1 = bf16_rne(f1);
                float hf0 = __uint_as_float(h0 << 16), hf1 = __uint_as_float(h1 << 16);
                unsigned l0 = bf16_rne(f0 - hf0), l1 = bf16_rne(f1 - hf1);
                hh[i] = (h1 << 16) | h0;
                ll[i] = (l1 << 16) | l0;
            }
            wh[kk] = *reinterpret_cast<short8*>(hh);
            wl[kk] = *reinterpret_cast<short8*>(ll);
        }

#pragma unroll 1
        for (int res = 0; res < 8; ++res) {
            const int S   = res & 3;
            const int off = ((res >> 2) << 2);       // 0 or 4
            const unsigned* base = &xls[S][0][0] + off;

            f32x4 acc = {0.f, 0.f, 0.f, 0.f};
#pragma unroll
            for (int kk = 0; kk < 8; ++kk) {
                const uint4* pp = reinterpret_cast<const uint4*>(base + preidx[kk]);
                uint4 pa = pp[0];
                uint4 pb = pp[1];
                unsigned p0 = pa.x, p1 = pa.y, p2 = pa.z, p3 = pa.w;
                unsigned p4 = pb.x, p5 = pb.y, p6 = pb.z, p7 = pb.w;
                unsigned ah_[4], al_[4];
                ah_[0] = (p1 & 0xFFFF0000u) | (p0 >> 16);
                ah_[1] = (p3 & 0xFFFF0000u) | (p2 >> 16);
                ah_[2] = (p5 & 0xFFFF0000u) | (p4 >> 16);
                ah_[3] = (p7 & 0xFFFF0000u) | (p6 >> 16);
                al_[0] = (p1 << 16) | (p0 & 0xFFFFu);
                al_[1] = (p3 << 16) | (p2 & 0xFFFFu);
                al_[2] = (p5 << 16) | (p4 & 0xFFFFu);
                al_[3] = (p7 << 16) | (p6 & 0xFFFFu);
                short8 ah = *reinterpret_cast<short8*>(ah_);
                short8 al = *reinterpret_cast<short8*>(al_);
                acc = __builtin_amdgcn_mfma_f32_16x16x32_bf16(ah, wh[kk], acc, 0, 0, 0);
                acc = __builtin_amdgcn_mfma_f32_16x16x32_bf16(al, wh[kk], acc, 0, 0, 0);
                acc = __builtin_amdgcn_mfma_f32_16x16x32_bf16(ah, wl[kk], acc, 0, 0, 0);
            }

            // ---- epilogue: repair borderline, set pool bits ----
#pragma unroll
            for (int reg = 0; reg < 4; ++reg) {
                float v = acc[reg];
                const int m   = q * 4 + reg;
                const int pcg = w0 + res + 8 * m;     // global pot col
                const bool valid = (fm < FM) && (pcg <= 2007);
                if (valid && __builtin_fabsf(v - THRESH) < MARGIN) {
                    float pot = 0.f;
#pragma unroll 1
                    for (int r2 = 0; r2 < 6; ++r2) {
                        const float* xr = x + ((size_t)tt * H_ + rowbase + j_p + r2) * WD_ + pcg;
                        const float* wr = Wg + (size_t)sec * FM * 240 + (size_t)fm * 240 + r2 * 40;
#pragma unroll 1
                        for (int c = 0; c < 40; ++c)
                            pot = fmaf(xr[c], wr[c], pot);
                    }
                    v = pot;
                }
                if (v > THRESH)
                    mask |= 1u << (reg * 8 + ft * 2 + (res >> 2));
            }
        }
    }

    lmask[j_p][L] = mask;
    __syncthreads();

    // ---- cross-wave OR + pooled write: 64 fm x 32 pooled cols ----
    for (int e = tid; e < 2048; e += 256) {
        const int fmo = e >> 5, p = e & 31;
        const int m = p >> 1, rg = p & 1, ftc = fmo >> 4, fn = fmo & 15;
        const int lane = (m >> 2) * 16 + fn;
        const int bitpos = (m & 3) * 8 + ftc * 2 + rg;
        const unsigned bits = lmask[0][lane] | lmask[1][lane] |
                              lmask[2][lane] | lmask[3][lane];
        const int pg = coltile * 32 + p;
        if (fmo < FM && pg < WP)
            out[((size_t)(sec * T_ + tt) * FM + fmo) * WP + pg] =
                ((bits >> bitpos) & 1u) ? 1.0f : 0.0f;
    }
}

// ---------------- Kernel B: init workspace ----------------
__global__ void init_kernel(int* __restrict__ ws)
{
    if (threadIdx.x < NSEC) ws[threadIdx.x] = 0x7fffffff;
}

// ---------------- Kernel C: first-spike scan + argmin reduce ----------------
__global__ __launch_bounds__(256) void scan_kernel(
    const float* __restrict__ pooled, int* __restrict__ ws)
{
    __shared__ int sk[256];
    const int sec = blockIdx.x / 99;
    const int bi  = blockIdx.x % 99;
    const int e   = bi * 256 + threadIdx.x;
    int key = 0x7fffffff;
    if (e < FM * WP) {
        const int fm = e / WP;
        const int wp = e % WP;
        const size_t base = ((size_t)(sec * T_) * FM + fm) * WP + wp;
        const size_t tstride = (size_t)FM * WP;
#pragma unroll 1
        for (int t = 0; t < T_; ++t) {
            if (pooled[base + t * tstride] > 0.f) { key = (t << 15) | e; break; }
        }
    }
    sk[threadIdx.x] = key;
    __syncthreads();
    for (int s = 128; s > 0; s >>= 1) {
        if (threadIdx.x < s) sk[threadIdx.x] = min(sk[threadIdx.x], sk[threadIdx.x + s]);
        __syncthreads();
    }
    if (threadIdx.x == 0) atomicMin(&ws[sec], sk[0]);
}

// ---------------- Kernel D: finalize winners ----------------
__global__ void finalize_kernel(const int* __restrict__ ws, float* __restrict__ out)
{
    const int i = threadIdx.x;
    if (i < NSEC) {
        const int key = ws[i];
        float feat;
        if (key == 0x7fffffff) feat = -1.0f;
        else                   feat = (float)((key & 32767) / WP);
        out[POOLED_SIZE + i] = feat;
    }
}

extern "C" void kernel_launch(void* const* d_in, const int* in_sizes, int n_in,
                              void* d_out, int out_size, void* d_ws, size_t ws_size,
                              hipStream_t stream) {
    const float* x  = (const float*)d_in[0];
    const float* Wg = (const float*)d_in[1];
    float* out = (float*)d_out;
    int*   ws  = (int*)d_ws;

    hipLaunchKernelGGL(init_kernel, dim3(1), dim3(64), 0, stream, ws);
    hipLaunchKernelGGL(conv_pool_kernel, dim3(4320), dim3(256), 0, stream, x, Wg, out);
    hipLaunchKernelGGL(scan_kernel, dim3(NSEC * 99), dim3(256), 0, stream, out, ws);
    hipLaunchKernelGGL(finalize_kernel, dim3(1), dim3(16), 0, stream, ws, out);
}